// Round 8
// baseline (64035.565 us; speedup 1.0000x reference)
//
#include <hip/hip_runtime.h>
#include <hip/hip_bf16.h>

#define NB 16
#define NBLK 128
#define TT 512
#define DD 20
#define WSTRIDE 1662976  // bytes per weight replica (prep layout size)

using bf16x8 = __attribute__((ext_vector_type(8))) short;
using f32x4  = __attribute__((ext_vector_type(4))) float;

typedef __attribute__((address_space(3))) unsigned int lds_uint;
typedef __attribute__((address_space(1))) unsigned int glob_uint;

// per-replica byte offsets
#define OFF_WIH0  0          // 1024x20  -> 64 tiles (stride 1024)
#define OFF_WHH0  65536      // 1024x256 -> 64 tiles x 8 kt (stride 8192)
#define OFF_WIH1  589824
#define OFF_WHH1  1114112
#define OFF_WPROJ 1638400    // 20x256 -> 2 tiles x 8 kt
#define OFF_B0    1654784
#define OFF_B1    1658880

// smem layout (bytes)
#define SM_PAN   0        // 2 x 32768 panel buffers (init overlays below)
#define SM_H0    65536    // 16*264*2 = 8448
#define SM_H1    73984    // 8448
#define SM_XB    82432    // 16*32*2 = 1024
#define SM_WPS   83456    // 16384 (W_proj resident)
#define SM_BS    99840    // 8192 (bias0|bias1 f32)
#define SM_TOTAL 108032
#define SM_CI    0        // overlay in panel area: [2][16][256] f32 = 32768
#define SM_ZB    40960    // overlay: 16*32 f32 = 2048

__device__ __forceinline__ float sigf(float x) { return 1.0f / (1.0f + __expf(-x)); }
__device__ __forceinline__ float tanhfast(float x) { return 1.0f - 2.0f / (__expf(2.0f * x) + 1.0f); }

__device__ __forceinline__ void stage16(const char* g, const char* l) {
    __builtin_amdgcn_global_load_lds((glob_uint*)g, (lds_uint*)l, 16, 0, 0);
}

// ---- prep: fp32 weights -> bf16, swizzled into MFMA B-fragment order (replica 0) ----
__global__ void prep_kernel(const float* __restrict__ wih0, const float* __restrict__ whh0,
                            const float* __restrict__ wih1, const float* __restrict__ whh1,
                            const float* __restrict__ wproj,
                            const float* __restrict__ bih0, const float* __restrict__ bhh0,
                            const float* __restrict__ bih1, const float* __restrict__ bhh1,
                            char* __restrict__ ws) {
    int idx = blockIdx.x * 256 + threadIdx.x;
    const float* src;
    __hip_bfloat16* dst;
    int e, N, K, nKt;
    if (idx < 32768)       { e = idx;          src = wih0;  N = 1024; K = 20;  nKt = 1; dst = (__hip_bfloat16*)(ws + OFF_WIH0); }
    else if (idx < 294912) { e = idx - 32768;  src = whh0;  N = 1024; K = 256; nKt = 8; dst = (__hip_bfloat16*)(ws + OFF_WHH0); }
    else if (idx < 557056) { e = idx - 294912; src = wih1;  N = 1024; K = 256; nKt = 8; dst = (__hip_bfloat16*)(ws + OFF_WIH1); }
    else if (idx < 819200) { e = idx - 557056; src = whh1;  N = 1024; K = 256; nKt = 8; dst = (__hip_bfloat16*)(ws + OFF_WHH1); }
    else if (idx < 827392) { e = idx - 819200; src = wproj; N = 20;   K = 256; nKt = 8; dst = (__hip_bfloat16*)(ws + OFF_WPROJ); }
    else if (idx < 828416) { int j = idx - 827392; ((float*)(ws + OFF_B0))[j] = bih0[j] + bhh0[j]; return; }
    else if (idx < 829440) { int j = idx - 828416; ((float*)(ws + OFF_B1))[j] = bih1[j] + bhh1[j]; return; }
    else return;
    int j    = e & 7;
    int lane = (e >> 3) & 63;
    int tile = e >> 9;
    int kt = tile % nKt;
    int nt = tile / nKt;
    int n = nt * 16 + (lane & 15);
    int k = kt * 32 + ((lane >> 4) << 3) + j;
    float v = (n < N && k < K) ? src[n * K + k] : 0.0f;
    dst[e] = __float2bfloat16(v);
}

// ---- replicate the prepared weight block across XCD-local copies ----
__global__ void replicate_kernel(char* __restrict__ ws, int nrep) {
    int i = blockIdx.x * 256 + threadIdx.x;           // 16B chunk index
    const int nchunk = WSTRIDE / 16;                  // 103936
    if (i >= nchunk) return;
    uint4 v = ((const uint4*)ws)[i];
    for (int r = 1; r < nrep; r++)
        ((uint4*)(ws + (size_t)r * WSTRIDE))[i] = v;
}

// ---- persistent decoder: 128 blocks x 512 threads, 16 batch rows/block ----
// waves 0-3: consumers (MFMA+EW, zero vmem in loop). waves 4-7: producers (DMA staging + y-output).
__global__ __launch_bounds__(512, 1) void decoder_kernel(
    const float* __restrict__ z, const float* __restrict__ w_lh, const float* __restrict__ b_lh,
    const float* __restrict__ w_lc, const float* __restrict__ b_lc,
    const float* __restrict__ b_proj, const char* __restrict__ ws, int nrep,
    float* __restrict__ out) {

    __shared__ __align__(16) char smem[SM_TOTAL];

    const int tid = threadIdx.x;
    const int blk = blockIdx.x;
    const int b0  = blk * NB;
    const char* wbase = ws + (size_t)((blk & 7) % nrep) * WSTRIDE;

    __hip_bfloat16* h0p = (__hip_bfloat16*)(smem + SM_H0);
    __hip_bfloat16* h1p = (__hip_bfloat16*)(smem + SM_H1);
    __hip_bfloat16* xbh = (__hip_bfloat16*)(smem + SM_XB);

    // ---- init: z, xb=0, W_proj, biases ----
    {
        float* zbf = (float*)(smem + SM_ZB);
        zbf[tid] = z[(b0 + (tid >> 5)) * 32 + (tid & 31)];
        if (tid < 256) ((unsigned int*)(smem + SM_XB))[tid] = 0;
        const bf16x8* sp = (const bf16x8*)(wbase + OFF_WPROJ);
        bf16x8* dp = (bf16x8*)(smem + SM_WPS);
        dp[tid] = sp[tid];
        dp[tid + 512] = sp[tid + 512];
        float* bs = (float*)(smem + SM_BS);
        const float* g0 = (const float*)(wbase + OFF_B0);
        const float* g1 = (const float*)(wbase + OFF_B1);
        bs[tid]        = g0[tid];
        bs[tid + 512]  = g0[tid + 512];
        bs[tid + 1024] = g1[tid];
        bs[tid + 1536] = g1[tid + 512];
    }
    __syncthreads();

    // ---- h/c init (fp32 VALU, K=32): 16 rows x 512 cols ----
    {
        float* ci = (float*)(smem + SM_CI);
        const float* zbf = (const float*)(smem + SM_ZB);
        for (int ii = 0; ii < 16; ii++) {
            int pi = ii * 512 + tid;
            int b = pi >> 9, col = pi & 511;
            float dh = b_lh[col], dc = b_lc[col];
            #pragma unroll 8
            for (int k = 0; k < 32; k++) {
                float zv = zbf[b * 32 + k];
                dh += zv * w_lh[col * 32 + k];
                dc += zv * w_lc[col * 32 + k];
            }
            if (col < 256) { h0p[b * 264 + col]         = __float2bfloat16(dh); ci[b * 256 + col]                = dc; }
            else           { h1p[b * 264 + (col - 256)] = __float2bfloat16(dh); ci[4096 + b * 256 + (col - 256)] = dc; }
        }
    }
    __syncthreads();

    const int wv = tid >> 6, ln = tid & 63;
    const int l15 = ln & 15, lq = ln >> 4;
    const int lnoff = ln * 16;

    // consumer state: wave wv(0..3) owns unit-tiles wv*4..wv*4+3, all 4 gates
    float c0a[4][4], c1a[4][4];
    if (wv < 4) {
        const float* ci = (const float*)(smem + SM_CI);
        #pragma unroll
        for (int j = 0; j < 4; j++)
            #pragma unroll
            for (int r = 0; r < 4; r++) {
                int u = (wv * 4 + j) * 16 + l15, m = lq * 4 + r;
                c0a[j][r] = ci[m * 256 + u];
                c1a[j][r] = ci[4096 + m * 256 + u];
            }
    }
    __syncthreads(); // CI/ZB overlays dead; panel area writable

    const char* W0x = wbase + OFF_WIH0;
    const char* W0h = wbase + OFF_WHH0;
    const char* W1x = wbase + OFF_WIH1;
    const char* W1h = wbase + OFF_WHH1;
    const char* wps_c = smem + SM_WPS;
    const char* h0c = smem + SM_H0;
    const char* h1c = smem + SM_H1;
    const char* xbc = smem + SM_XB;
    const float* bsl = (const float*)(smem + SM_BS);

    // producer y-output setup (waves 4,5 handle col-tiles 0,1)
    const int pt = wv - 4;
    const int pc_col = pt * 16 + l15;
    const float bpj = (wv >= 4 && wv <= 5 && pc_col < 20) ? b_proj[pc_col] : 0.0f;

    // producer: stage panel idx (wraps at 50) into buf; wave pw=wv-4 stages tiles pw*8..pw*8+7
    auto stagePanelIdx = [&](int idx, int buf) {
        if (idx >= 50) idx -= 50;
        const char* Wb; int stride, kt, half;
        if (idx < 16)      { Wb = W0h; stride = 8192; kt = idx >> 1;        half = idx & 1; }
        else if (idx < 18) { Wb = W0x; stride = 1024; kt = 0;               half = idx - 16; }
        else if (idx < 34) { Wb = W1x; stride = 8192; kt = (idx - 18) >> 1; half = (idx - 18) & 1; }
        else               { Wb = W1h; stride = 8192; kt = (idx - 34) >> 1; half = (idx - 34) & 1; }
        const int pw = wv - 4;
        const char* g = Wb + (half * 32 + pw * 8) * stride + kt * 1024 + lnoff;
        char* l = smem + SM_PAN + buf * 32768 + (pw * 8) * 1024;
        #pragma unroll
        for (int j = 0; j < 8; j++)
            stage16(g + j * stride, l + j * 1024);
    };

    // producer phase C (waves 4,5): y(t-1) -> out, x(t) -> xb
    auto phaseC = [&](int t) {
        f32x4 py = {bpj, bpj, bpj, bpj};
        #pragma unroll
        for (int kt = 0; kt < 8; kt++) {
            bf16x8 ah = *(const bf16x8*)(h1c + l15 * 528 + kt * 64 + lq * 16);
            bf16x8 wf = *(const bf16x8*)(wps_c + pt * 8192 + kt * 1024 + lnoff);
            py = __builtin_amdgcn_mfma_f32_16x16x32_bf16(ah, wf, py, 0, 0, 0);
        }
        if (pc_col < 20) {
            #pragma unroll
            for (int r = 0; r < 4; r++) {
                int row = lq * 4 + r;
                out[((size_t)(b0 + row) * TT + (t - 1)) * DD + pc_col] = py[r];
                xbh[row * 32 + pc_col] = __float2bfloat16(py[r]);
            }
        }
    };

    f32x4 acc[4][4]; // [gate][j]

    // ---- prologue: producers stage panel 0 ----
    if (wv >= 4) stagePanelIdx(0, 0);
    __syncthreads(); // panel 0 deposited (producer drain)

    #pragma unroll 1
    for (int t = 0; t < TT; t++) {
        #pragma unroll 1
        for (int p = 0; p < 50; p++) {
            if (wv >= 4) {
                // ======== producer ========
                stagePanelIdx(p + 1, (p + 1) & 1);
                if (p == 0 && t > 0 && wv <= 5) phaseC(t);
            } else {
                // ======== consumer ========
                if (p == 0 || p == 18) {
                    const float* bb = bsl + (p == 0 ? 0 : 1024);
                    #pragma unroll
                    for (int g = 0; g < 4; g++)
                        #pragma unroll
                        for (int j = 0; j < 4; j++) {
                            float b = bb[g * 256 + (wv * 4 + j) * 16 + l15];
                            f32x4 v = {b, b, b, b};
                            acc[g][j] = v;
                        }
                }
                int kt, half; const char* asrc; bool isx = false;
                if (p < 16)      { kt = p >> 1;        half = p & 1;        asrc = h0c; }
                else if (p < 18) { kt = 0;             half = p - 16;       isx = true; asrc = xbc; }
                else if (p < 34) { kt = (p - 18) >> 1; half = (p - 18) & 1; asrc = h0c; }
                else             { kt = (p - 34) >> 1; half = (p - 34) & 1; asrc = h1c; }
                bf16x8 af = isx ? *(const bf16x8*)(xbc + l15 * 64 + lq * 16)
                                : *(const bf16x8*)(asrc + l15 * 528 + kt * 64 + lq * 16);
                const char* pb = smem + SM_PAN + (p & 1) * 32768;
                #pragma unroll
                for (int sub = 0; sub < 2; sub++)
                    #pragma unroll
                    for (int j = 0; j < 4; j++) {
                        bf16x8 wt = *(const bf16x8*)(pb + (sub * 16 + wv * 4 + j) * 1024 + lnoff);
                        acc[2 * half + sub][j] =
                            __builtin_amdgcn_mfma_f32_16x16x32_bf16(af, wt, acc[2 * half + sub][j], 0, 0, 0);
                    }
                if (p == 17) {
                    // EW-A: c0,h0 update
                    #pragma unroll
                    for (int j = 0; j < 4; j++)
                        #pragma unroll
                        for (int r = 0; r < 4; r++) {
                            float cn = sigf(acc[1][j][r]) * c0a[j][r] + sigf(acc[0][j][r]) * tanhfast(acc[2][j][r]);
                            float hn = sigf(acc[3][j][r]) * tanhfast(cn);
                            c0a[j][r] = cn;
                            h0p[(lq * 4 + r) * 264 + (wv * 4 + j) * 16 + l15] = __float2bfloat16(hn);
                        }
                } else if (p == 49) {
                    // EW-B: c1,h1 update
                    #pragma unroll
                    for (int j = 0; j < 4; j++)
                        #pragma unroll
                        for (int r = 0; r < 4; r++) {
                            float cn = sigf(acc[1][j][r]) * c1a[j][r] + sigf(acc[0][j][r]) * tanhfast(acc[2][j][r]);
                            float hn = sigf(acc[3][j][r]) * tanhfast(cn);
                            c1a[j][r] = cn;
                            h1p[(lq * 4 + r) * 264 + (wv * 4 + j) * 16 + l15] = __float2bfloat16(hn);
                        }
                }
            }
            __syncthreads();
        }
    }

    // final y(TT-1)
    if (wv >= 4 && wv <= 5) phaseC(TT);
}

extern "C" void kernel_launch(void* const* d_in, const int* in_sizes, int n_in,
                              void* d_out, int out_size, void* d_ws, size_t ws_size,
                              hipStream_t stream) {
    const float* z      = (const float*)d_in[0];
    const float* w_lh   = (const float*)d_in[3];
    const float* b_lh   = (const float*)d_in[4];
    const float* w_lc   = (const float*)d_in[5];
    const float* b_lc   = (const float*)d_in[6];
    const float* w_ih0  = (const float*)d_in[7];
    const float* w_hh0  = (const float*)d_in[8];
    const float* b_ih0  = (const float*)d_in[9];
    const float* b_hh0  = (const float*)d_in[10];
    const float* w_ih1  = (const float*)d_in[11];
    const float* w_hh1  = (const float*)d_in[12];
    const float* b_ih1  = (const float*)d_in[13];
    const float* b_hh1  = (const float*)d_in[14];
    const float* w_proj = (const float*)d_in[15];
    const float* b_proj = (const float*)d_in[16];
    char* ws = (char*)d_ws;
    float* out = (float*)d_out;

    int nrep = (int)(ws_size / (size_t)WSTRIDE);
    if (nrep < 1) nrep = 1;
    if (nrep > 8) nrep = 8;

    prep_kernel<<<3240, 256, 0, stream>>>(w_ih0, w_hh0, w_ih1, w_hh1, w_proj,
                                          b_ih0, b_hh0, b_ih1, b_hh1, ws);
    if (nrep > 1)
        replicate_kernel<<<(WSTRIDE / 16 + 255) / 256, 256, 0, stream>>>(ws, nrep);
    decoder_kernel<<<NBLK, 512, 0, stream>>>(z, w_lh, b_lh, w_lc, b_lc, b_proj, ws, nrep, out);
}

// Round 9
// 18928.627 us; speedup vs baseline: 3.3830x; 3.3830x over previous
//
#include <hip/hip_runtime.h>
#include <hip/hip_bf16.h>

#define NB 16
#define NBLK 128
#define TT 512
#define DD 20
#define NPAN (TT * 50)
#define WSTRIDE 1662976  // bytes per weight replica

using bf16x8 = __attribute__((ext_vector_type(8))) short;
using f32x4  = __attribute__((ext_vector_type(4))) float;

typedef __attribute__((address_space(3))) unsigned int lds_uint;
typedef __attribute__((address_space(1))) unsigned int glob_uint;

// per-replica byte offsets
#define OFF_WIH0  0
#define OFF_WHH0  65536
#define OFF_WIH1  589824
#define OFF_WHH1  1114112
#define OFF_WPROJ 1638400
#define OFF_B0    1654784
#define OFF_B1    1658880

// smem layout (bytes)
#define SM_PAN   0        // 3 ring slots x 32768 = 98304 (CI/ZB overlay during init)
#define SM_H0    98304    // 16*264*2 = 8448
#define SM_H1    106752   // 8448
#define SM_XB    115200   // 1024
#define SM_WPS   116224   // 16384
#define SM_TOTAL 132608
#define SM_CI    0        // overlay: [2][16][256] f32 = 32768
#define SM_ZB    40960    // overlay: 16*32 f32 = 2048

__device__ __forceinline__ float sigf(float x) { return 1.0f / (1.0f + __expf(-x)); }
__device__ __forceinline__ float tanhfast(float x) { return 1.0f - 2.0f / (__expf(2.0f * x) + 1.0f); }

__device__ __forceinline__ void stage16(const char* g, const char* l) {
    __builtin_amdgcn_global_load_lds((glob_uint*)g, (lds_uint*)l, 16, 0, 0);
}

// ---- prep: fp32 weights -> bf16, swizzled into MFMA B-fragment order ----
__global__ void prep_kernel(const float* __restrict__ wih0, const float* __restrict__ whh0,
                            const float* __restrict__ wih1, const float* __restrict__ whh1,
                            const float* __restrict__ wproj,
                            const float* __restrict__ bih0, const float* __restrict__ bhh0,
                            const float* __restrict__ bih1, const float* __restrict__ bhh1,
                            char* __restrict__ ws) {
    int idx = blockIdx.x * 256 + threadIdx.x;
    const float* src;
    __hip_bfloat16* dst;
    int e, N, K, nKt;
    if (idx < 32768)       { e = idx;          src = wih0;  N = 1024; K = 20;  nKt = 1; dst = (__hip_bfloat16*)(ws + OFF_WIH0); }
    else if (idx < 294912) { e = idx - 32768;  src = whh0;  N = 1024; K = 256; nKt = 8; dst = (__hip_bfloat16*)(ws + OFF_WHH0); }
    else if (idx < 557056) { e = idx - 294912; src = wih1;  N = 1024; K = 256; nKt = 8; dst = (__hip_bfloat16*)(ws + OFF_WIH1); }
    else if (idx < 819200) { e = idx - 557056; src = whh1;  N = 1024; K = 256; nKt = 8; dst = (__hip_bfloat16*)(ws + OFF_WHH1); }
    else if (idx < 827392) { e = idx - 819200; src = wproj; N = 20;   K = 256; nKt = 8; dst = (__hip_bfloat16*)(ws + OFF_WPROJ); }
    else if (idx < 828416) { int j = idx - 827392; ((float*)(ws + OFF_B0))[j] = bih0[j] + bhh0[j]; return; }
    else if (idx < 829440) { int j = idx - 828416; ((float*)(ws + OFF_B1))[j] = bih1[j] + bhh1[j]; return; }
    else return;
    int j    = e & 7;
    int lane = (e >> 3) & 63;
    int tile = e >> 9;
    int kt = tile % nKt;
    int nt = tile / nKt;
    int n = nt * 16 + (lane & 15);
    int k = kt * 32 + ((lane >> 4) << 3) + j;
    float v = (n < N && k < K) ? src[n * K + k] : 0.0f;
    dst[e] = __float2bfloat16(v);
}

__global__ void replicate_kernel(char* __restrict__ ws, int nrep) {
    int i = blockIdx.x * 256 + threadIdx.x;
    const int nchunk = WSTRIDE / 16;
    if (i >= nchunk) return;
    uint4 v = ((const uint4*)ws)[i];
    for (int r = 1; r < nrep; r++)
        ((uint4*)(ws + (size_t)r * WSTRIDE))[i] = v;
}

// ---- persistent decoder: 128 blocks x 512 threads, 16 batch rows/block ----
// waves 0-3: consumers (pure LDS+MFMA, no vmem). waves 4-7: producers (endless DMA pump).
__global__ __launch_bounds__(512, 1) void decoder_kernel(
    const float* __restrict__ z, const float* __restrict__ w_lh, const float* __restrict__ b_lh,
    const float* __restrict__ w_lc, const float* __restrict__ b_lc,
    const float* __restrict__ b_proj, const char* __restrict__ ws, int nrep,
    float* __restrict__ out) {

    __shared__ __align__(16) char smem[SM_TOTAL];
    __shared__ int g_rdy[12];  // [slot][producer-wave] ready sequence (value = panel_idx+1)
    __shared__ int g_rel[3];   // per-slot cumulative consumer releases
    __shared__ int g_cbar;     // consumer spin-barrier counter

    const int tid = threadIdx.x;
    const int blk = blockIdx.x;
    const int b0  = blk * NB;
    const char* wbase = ws + (size_t)((blk & 7) % nrep) * WSTRIDE;

    __hip_bfloat16* h0p = (__hip_bfloat16*)(smem + SM_H0);
    __hip_bfloat16* h1p = (__hip_bfloat16*)(smem + SM_H1);
    __hip_bfloat16* xbh = (__hip_bfloat16*)(smem + SM_XB);

    // ---- init ----
    if (tid < 12) g_rdy[tid] = 0;
    if (tid < 3)  g_rel[tid] = 0;
    if (tid == 0) g_cbar = 0;
    {
        float* zbf = (float*)(smem + SM_ZB);
        zbf[tid] = z[(b0 + (tid >> 5)) * 32 + (tid & 31)];
        if (tid < 256) ((unsigned int*)(smem + SM_XB))[tid] = 0;
        const bf16x8* sp = (const bf16x8*)(wbase + OFF_WPROJ);
        bf16x8* dp = (bf16x8*)(smem + SM_WPS);
        dp[tid] = sp[tid];
        dp[tid + 512] = sp[tid + 512];
    }
    __syncthreads();

    // h/c init (fp32 VALU, K=32)
    {
        float* ci = (float*)(smem + SM_CI);
        const float* zbf = (const float*)(smem + SM_ZB);
        for (int ii = 0; ii < 16; ii++) {
            int pi = ii * 512 + tid;
            int b = pi >> 9, col = pi & 511;
            float dh = b_lh[col], dc = b_lc[col];
            #pragma unroll 8
            for (int k = 0; k < 32; k++) {
                float zv = zbf[b * 32 + k];
                dh += zv * w_lh[col * 32 + k];
                dc += zv * w_lc[col * 32 + k];
            }
            if (col < 256) { h0p[b * 264 + col]         = __float2bfloat16(dh); ci[b * 256 + col]                = dc; }
            else           { h1p[b * 264 + (col - 256)] = __float2bfloat16(dh); ci[4096 + b * 256 + (col - 256)] = dc; }
        }
    }
    __syncthreads();

    const int wv = tid >> 6, ln = tid & 63;
    const int l15 = ln & 15, lq = ln >> 4;
    const int lnoff = ln * 16;

    // consumer-only state loaded BEFORE the overlay dies
    float c0a[4][4], c1a[4][4], bs0r[4][4], bs1r[4][4];
    if (wv < 4) {
        const float* ci = (const float*)(smem + SM_CI);
        const float* bg0 = (const float*)(wbase + OFF_B0);
        const float* bg1 = (const float*)(wbase + OFF_B1);
        #pragma unroll
        for (int g = 0; g < 4; g++)
            #pragma unroll
            for (int j = 0; j < 4; j++) {
                int u = (wv * 4 + j) * 16 + l15;
                bs0r[g][j] = bg0[g * 256 + u];
                bs1r[g][j] = bg1[g * 256 + u];
                if (g < 1) {
                    c0a[j][0] = 0; // placeholder; real fill below
                }
            }
        #pragma unroll
        for (int j = 0; j < 4; j++)
            #pragma unroll
            for (int r = 0; r < 4; r++) {
                int u = (wv * 4 + j) * 16 + l15, m = lq * 4 + r;
                c0a[j][r] = ci[m * 256 + u];
                c1a[j][r] = ci[4096 + m * 256 + u];
            }
    }
    __syncthreads(); // overlays dead; producers may write panel ring from here

    const char* W0x = wbase + OFF_WIH0;
    const char* W0h = wbase + OFF_WHH0;
    const char* W1x = wbase + OFF_WIH1;
    const char* W1h = wbase + OFF_WHH1;
    const char* wps_c = smem + SM_WPS;
    const char* h0c = smem + SM_H0;
    const char* h1c = smem + SM_H1;
    const char* xbc = smem + SM_XB;

    if (wv >= 4) {
        // ================= PRODUCER =================
        const int pw = wv - 4;
        int sl = 0, pi = 0, psl = 0, relt = -4;
        #pragma unroll 1
        for (int p = 0; p < NPAN; p++) {
            if (sl == 0) relt += 4;
            if (p >= 3) {
                volatile int* r = &g_rel[sl];
                while (*r < relt) {}
            }
            const char* Wb; int stride, kt2, half2;
            if (pi < 16)      { Wb = W0h; stride = 8192; kt2 = pi >> 1;        half2 = pi & 1; }
            else if (pi < 18) { Wb = W0x; stride = 1024; kt2 = 0;              half2 = pi - 16; }
            else if (pi < 34) { Wb = W1x; stride = 8192; kt2 = (pi - 18) >> 1; half2 = (pi - 18) & 1; }
            else              { Wb = W1h; stride = 8192; kt2 = (pi - 34) >> 1; half2 = (pi - 34) & 1; }
            const char* g = Wb + (half2 * 32 + pw * 8) * stride + kt2 * 1024 + lnoff;
            char* l = smem + SM_PAN + sl * 32768 + (pw * 8) * 1024;
            #pragma unroll
            for (int j = 0; j < 8; j++)
                stage16(g + j * stride, l + j * 1024);
            asm volatile("s_waitcnt vmcnt(8)" ::: "memory");
            if (p >= 1) ((volatile int*)g_rdy)[psl * 4 + pw] = p;  // panel p-1 ready
            psl = sl;
            sl = (sl == 2) ? 0 : sl + 1;
            if (++pi == 50) pi = 0;
        }
        asm volatile("s_waitcnt vmcnt(0)" ::: "memory");
        ((volatile int*)g_rdy)[psl * 4 + pw] = NPAN;
        return;
    }

    // ================= CONSUMER =================
    f32x4 acc[4][4];
    int pgt = 1, sl = 0, cbt = 0;

#define CONSUME(HALF, KT, ASRC, ISX) {                                          \
    volatile int* _r = g_rdy + sl * 4;                                          \
    while (_r[0] < pgt || _r[1] < pgt || _r[2] < pgt || _r[3] < pgt) {}         \
    asm volatile("" ::: "memory");                                              \
    const char* pb = smem + SM_PAN + sl * 32768;                                \
    bf16x8 af;                                                                  \
    if (ISX) af = *(const bf16x8*)(xbc + l15 * 64 + lq * 16);                   \
    else     af = *(const bf16x8*)((ASRC) + l15 * 528 + (KT) * 64 + lq * 16);   \
    _Pragma("unroll")                                                           \
    for (int sub = 0; sub < 2; sub++)                                           \
        _Pragma("unroll")                                                       \
        for (int j = 0; j < 4; j++) {                                           \
            bf16x8 wt = *(const bf16x8*)(pb + (sub * 16 + wv * 4 + j) * 1024 + lnoff); \
            acc[2 * (HALF) + sub][j] =                                          \
                __builtin_amdgcn_mfma_f32_16x16x32_bf16(af, wt, acc[2 * (HALF) + sub][j], 0, 0, 0); \
        }                                                                       \
    asm volatile("s_waitcnt lgkmcnt(0)" ::: "memory");                          \
    if (ln == 0) atomicAdd(&g_rel[sl], 1);                                      \
    pgt++; sl = (sl == 2) ? 0 : sl + 1;                                         \
}

#define CBAR {                                                                  \
    cbt += 4;                                                                   \
    asm volatile("s_waitcnt lgkmcnt(0)" ::: "memory");                          \
    if (ln == 0) atomicAdd(&g_cbar, 1);                                         \
    volatile int* _c = &g_cbar;                                                 \
    while (*_c < cbt) {}                                                        \
    asm volatile("" ::: "memory");                                              \
}

#define INIT_ACC(BS) {                                                          \
    _Pragma("unroll")                                                           \
    for (int g = 0; g < 4; g++)                                                 \
        _Pragma("unroll")                                                       \
        for (int j = 0; j < 4; j++) {                                           \
            f32x4 v = {BS[g][j], BS[g][j], BS[g][j], BS[g][j]};                 \
            acc[g][j] = v;                                                      \
        }                                                                       \
}

    const int pc_col = wv * 16 + l15;  // waves 0,1 emit y cols
    const float bpj = (wv < 2 && pc_col < 20) ? b_proj[pc_col] : 0.0f;

    #pragma unroll 1
    for (int t = 0; t < TT; t++) {
        // ---- phase A: gates0 ----
        INIT_ACC(bs0r);
        CONSUME(0, 0, h0c, false)  CONSUME(1, 0, h0c, false)
        CONSUME(0, 1, h0c, false)  CONSUME(1, 1, h0c, false)
        CONSUME(0, 2, h0c, false)  CONSUME(1, 2, h0c, false)
        CONSUME(0, 3, h0c, false)  CONSUME(1, 3, h0c, false)
        CONSUME(0, 4, h0c, false)  CONSUME(1, 4, h0c, false)
        CONSUME(0, 5, h0c, false)  CONSUME(1, 5, h0c, false)
        CONSUME(0, 6, h0c, false)  CONSUME(1, 6, h0c, false)
        CONSUME(0, 7, h0c, false)  CONSUME(1, 7, h0c, false)
        CONSUME(0, 0, xbc, true)   CONSUME(1, 0, xbc, true)
        // EW-A
        #pragma unroll
        for (int j = 0; j < 4; j++)
            #pragma unroll
            for (int r = 0; r < 4; r++) {
                float cn = sigf(acc[1][j][r]) * c0a[j][r] + sigf(acc[0][j][r]) * tanhfast(acc[2][j][r]);
                float hn = sigf(acc[3][j][r]) * tanhfast(cn);
                c0a[j][r] = cn;
                h0p[(lq * 4 + r) * 264 + (wv * 4 + j) * 16 + l15] = __float2bfloat16(hn);
            }
        CBAR
        // ---- phase B: gates1 ----
        INIT_ACC(bs1r);
        CONSUME(0, 0, h0c, false)  CONSUME(1, 0, h0c, false)
        CONSUME(0, 1, h0c, false)  CONSUME(1, 1, h0c, false)
        CONSUME(0, 2, h0c, false)  CONSUME(1, 2, h0c, false)
        CONSUME(0, 3, h0c, false)  CONSUME(1, 3, h0c, false)
        CONSUME(0, 4, h0c, false)  CONSUME(1, 4, h0c, false)
        CONSUME(0, 5, h0c, false)  CONSUME(1, 5, h0c, false)
        CONSUME(0, 6, h0c, false)  CONSUME(1, 6, h0c, false)
        CONSUME(0, 7, h0c, false)  CONSUME(1, 7, h0c, false)
        CONSUME(0, 0, h1c, false)  CONSUME(1, 0, h1c, false)
        CONSUME(0, 1, h1c, false)  CONSUME(1, 1, h1c, false)
        CONSUME(0, 2, h1c, false)  CONSUME(1, 2, h1c, false)
        CONSUME(0, 3, h1c, false)  CONSUME(1, 3, h1c, false)
        CONSUME(0, 4, h1c, false)  CONSUME(1, 4, h1c, false)
        CONSUME(0, 5, h1c, false)  CONSUME(1, 5, h1c, false)
        CONSUME(0, 6, h1c, false)  CONSUME(1, 6, h1c, false)
        CONSUME(0, 7, h1c, false)  CONSUME(1, 7, h1c, false)
        // EW-B
        #pragma unroll
        for (int j = 0; j < 4; j++)
            #pragma unroll
            for (int r = 0; r < 4; r++) {
                float cn = sigf(acc[1][j][r]) * c1a[j][r] + sigf(acc[0][j][r]) * tanhfast(acc[2][j][r]);
                float hn = sigf(acc[3][j][r]) * tanhfast(cn);
                c1a[j][r] = cn;
                h1p[(lq * 4 + r) * 264 + (wv * 4 + j) * 16 + l15] = __float2bfloat16(hn);
            }
        CBAR
        // phase C: y(t) from h1(t); x(t+1) -> xb  (waves 0,1)
        if (wv < 2) {
            f32x4 py = {bpj, bpj, bpj, bpj};
            #pragma unroll
            for (int kt = 0; kt < 8; kt++) {
                bf16x8 ah = *(const bf16x8*)(h1c + l15 * 528 + kt * 64 + lq * 16);
                bf16x8 wf = *(const bf16x8*)(wps_c + wv * 8192 + kt * 1024 + lnoff);
                py = __builtin_amdgcn_mfma_f32_16x16x32_bf16(ah, wf, py, 0, 0, 0);
            }
            if (pc_col < 20) {
                #pragma unroll
                for (int r = 0; r < 4; r++) {
                    int row = lq * 4 + r;
                    out[((size_t)(b0 + row) * TT + t) * DD + pc_col] = py[r];
                    xbh[row * 32 + pc_col] = __float2bfloat16(py[r]);
                }
            }
        }
        CBAR
    }
#undef CONSUME
#undef CBAR
#undef INIT_ACC
}

extern "C" void kernel_launch(void* const* d_in, const int* in_sizes, int n_in,
                              void* d_out, int out_size, void* d_ws, size_t ws_size,
                              hipStream_t stream) {
    const float* z      = (const float*)d_in[0];
    const float* w_lh   = (const float*)d_in[3];
    const float* b_lh   = (const float*)d_in[4];
    const float* w_lc   = (const float*)d_in[5];
    const float* b_lc   = (const float*)d_in[6];
    const float* w_ih0  = (const float*)d_in[7];
    const float* w_hh0  = (const float*)d_in[8];
    const float* b_ih0  = (const float*)d_in[9];
    const float* b_hh0  = (const float*)d_in[10];
    const float* w_ih1  = (const float*)d_in[11];
    const float* w_hh1  = (const float*)d_in[12];
    const float* b_ih1  = (const float*)d_in[13];
    const float* b_hh1  = (const float*)d_in[14];
    const float* w_proj = (const float*)d_in[15];
    const float* b_proj = (const float*)d_in[16];
    char* ws = (char*)d_ws;
    float* out = (float*)d_out;

    int nrep = (int)(ws_size / (size_t)WSTRIDE);
    if (nrep < 1) nrep = 1;
    if (nrep > 8) nrep = 8;

    prep_kernel<<<3240, 256, 0, stream>>>(w_ih0, w_hh0, w_ih1, w_hh1, w_proj,
                                          b_ih0, b_hh0, b_ih1, b_hh1, ws);
    if (nrep > 1)
        replicate_kernel<<<(WSTRIDE / 16 + 255) / 256, 256, 0, stream>>>(ws, nrep);
    decoder_kernel<<<NBLK, 512, 0, stream>>>(z, w_lh, b_lh, w_lc, b_lc, b_proj, ws, nrep, out);
}